// Round 8
// baseline (192.086 us; speedup 1.0000x reference)
//
#include <hip/hip_runtime.h>
#include <hip/hip_bf16.h>

using bf16x8 = __attribute__((ext_vector_type(8))) short;
using f32x4  = __attribute__((ext_vector_type(4))) float;
using u32x4  = __attribute__((ext_vector_type(4))) unsigned int;
typedef unsigned short u16;
typedef unsigned int u32;

#define NB    2
#define NC    128
#define NPTS  65536
#define MTOT  (NB*NPTS)     // 131072
#define NTILE (MTOT/64)     // 2048

// round-to-nearest-even fp32 -> bf16 (bit pattern)
static __device__ __forceinline__ u16 f2bf(float f) {
    u32 u = __float_as_uint(f);
    u32 r = (u + 0x7FFFu + ((u >> 16) & 1u)) >> 16;
    return (u16)r;
}
static __device__ __forceinline__ float bflo(u32 d) { return __uint_as_float(d << 16); }
static __device__ __forceinline__ float bfhi(u32 d) { return __uint_as_float(d & 0xFFFF0000u); }

// ---------------- prep body: pack weights fragment-major (8 x 64-col panels) ----------------
static __device__ __forceinline__ void prep_body(
    int id,
    const float* __restrict__ W1, const float* __restrict__ W2,
    const float* __restrict__ b1, const float* __restrict__ g1, const float* __restrict__ be1,
    const float* __restrict__ m1, const float* __restrict__ v1,
    const float* __restrict__ b2, const float* __restrict__ g2, const float* __restrict__ be2,
    const float* __restrict__ m2, const float* __restrict__ v2,
    u16* __restrict__ W1p, u16* __restrict__ W2p,
    float* __restrict__ s1, float* __restrict__ t1,
    float* __restrict__ s2, float* __restrict__ t2)
{
    {   // W2p
        int l = id & 63, nf = (id >> 6) & 3, kk = (id >> 8) & 15, w = id >> 12;
        int n  = w * 64 + nf * 16 + (l & 15);
        int c0 = kk * 32 + (l >> 4) * 8;
        #pragma unroll
        for (int j = 0; j < 8; ++j)
            W2p[id * 8 + j] = f2bf(W2[(size_t)(c0 + j) * 512 + n]);
    }
    if (id < 8192) {   // W1p
        int l = id & 63, nf = (id >> 6) & 3, kk = (id >> 8) & 3, w = id >> 10;
        int n  = w * 64 + nf * 16 + (l & 15);
        int c0 = kk * 32 + (l >> 4) * 8;
        #pragma unroll
        for (int j = 0; j < 8; ++j)
            W1p[id * 8 + j] = f2bf(W1[(size_t)(c0 + j) * 512 + n]);
    }
    if (id < 512) {
        float s = g1[id] * rsqrtf(v1[id] + 1e-5f);
        s1[id] = s;
        t1[id] = (b1[id] - m1[id]) * s + be1[id];
        float ss = g2[id] * rsqrtf(v2[id] + 1e-5f);
        s2[id] = ss;
        t2[id] = (b2[id] - m2[id]) * ss + be2[id];
    }
}

__global__ void prep_kernel(
    const float* __restrict__ W1, const float* __restrict__ W2,
    const float* __restrict__ b1, const float* __restrict__ g1, const float* __restrict__ be1,
    const float* __restrict__ m1, const float* __restrict__ v1,
    const float* __restrict__ b2, const float* __restrict__ g2, const float* __restrict__ be2,
    const float* __restrict__ m2, const float* __restrict__ v2,
    u16* __restrict__ W1p, u16* __restrict__ W2p,
    float* __restrict__ s1, float* __restrict__ t1,
    float* __restrict__ s2, float* __restrict__ t2)
{
    prep_body(blockIdx.x * 256 + threadIdx.x, W1, W2, b1, g1, be1, m1, v1,
              b2, g2, be2, m2, v2, W1p, W2p, s1, t1, s2, t2);
}

// ---------------- volume transpose (+ prep in tail blocks) ----------------
__global__ __launch_bounds__(256) void transpose_kernel(
    const float* __restrict__ feat, u16* __restrict__ featT,
    const float* __restrict__ W1, const float* __restrict__ W2,
    const float* __restrict__ b1, const float* __restrict__ g1, const float* __restrict__ be1,
    const float* __restrict__ m1, const float* __restrict__ v1,
    const float* __restrict__ b2, const float* __restrict__ g2, const float* __restrict__ be2,
    const float* __restrict__ m2, const float* __restrict__ v2,
    u16* __restrict__ W1p, u16* __restrict__ W2p,
    float* __restrict__ s1, float* __restrict__ t1,
    float* __restrict__ s2, float* __restrict__ t2)
{
    __shared__ float tile[128][33];
    int blk = blockIdx.x;               // 0..16511
    if (blk >= 16384) {                 // prep tail
        prep_body((blk - 16384) * 256 + threadIdx.x, W1, W2, b1, g1, be1, m1, v1,
                  b2, g2, be2, m2, v2, W1p, W2p, s1, t1, s2, t2);
        return;
    }
    int b   = blk >> 13;
    int v0  = (blk & 8191) << 5;        // 32 voxels per block
    int t   = threadIdx.x;
    const float* fb = feat + ((size_t)b << 25) + v0;
    int c_l = t >> 3, f4 = t & 7;
    #pragma unroll
    for (int r = 0; r < 4; ++r) {
        int c = c_l + 32 * r;
        float4 v = *(const float4*)(fb + ((size_t)c << 18) + f4 * 4);
        tile[c][f4 * 4 + 0] = v.x;
        tile[c][f4 * 4 + 1] = v.y;
        tile[c][f4 * 4 + 2] = v.z;
        tile[c][f4 * 4 + 3] = v.w;
    }
    __syncthreads();
    u32* outp = (u32*)(featT + (((size_t)b << 18) + v0) * 128);
    #pragma unroll
    for (int r = 0; r < 2; ++r) {
        int idx = t + 256 * r;          // 0..511
        int v   = idx >> 4;             // voxel 0..31
        int c4  = idx & 15;             // 8-channel group
        u32x4 o;
        #pragma unroll
        for (int k = 0; k < 4; ++k) {
            float lo = tile[8 * c4 + 2 * k + 0][v];
            float hi = tile[8 * c4 + 2 * k + 1][v];
            o[k] = (u32)f2bf(lo) | ((u32)f2bf(hi) << 16);
        }
        *(u32x4*)(outp + (size_t)v * 64 + c4 * 4) = o;
    }
}

// ---------------- fused sample + MLP: 512 threads / 8 waves, 64 points per block ----------------
template<bool SAMP>
__global__ __launch_bounds__(512, 4) void fused_kernel(
    const u16* __restrict__ featT, const u16* __restrict__ feats,
    const float* __restrict__ qp,
    const u16* __restrict__ W1p, const u16* __restrict__ W2p,
    const float* __restrict__ s1, const float* __restrict__ t1,
    const float* __restrict__ s2, const float* __restrict__ t2,
    const float* __restrict__ W3, const float* __restrict__ b3,
    float* __restrict__ out)
{
    __shared__ u16 h1[64 * 512];      // 64 KiB; first 16 KiB doubles as the A-tile
    __shared__ float outb[512];       // 2 KiB
    u16* atile = h1;                  // [64 rows][16 chunks of 8 bf16], chunk ^= (row&7)

    const int tidx = threadIdx.x;
    const int w    = tidx >> 6;       // 0..7
    const int l    = tidx & 63;
    const int l15  = l & 15;
    const int lq   = l >> 4;
    const int m0   = blockIdx.x * 64;
    const int n0   = w * 64;

    const u16* B1 = W1p + (size_t)(w * 4)  * 4 * 512;
    const u16* B2 = W2p + (size_t)(w * 16) * 4 * 512;

#define LOADB1(dst, kk) { _Pragma("unroll") for (int nf = 0; nf < 4; ++nf) \
    (dst)[nf] = *(const bf16x8*)(B1 + ((kk) * 4 + nf) * 512 + l * 8); }
#define LOADB2(dst, kk) { _Pragma("unroll") for (int nf = 0; nf < 4; ++nf) \
    (dst)[nf] = *(const bf16x8*)(B2 + ((kk) * 4 + nf) * 512 + l * 8); }
#define LDSA(dst, kk) { _Pragma("unroll") for (int mf = 0; mf < 4; ++mf) { \
    int row = mf * 16 + l15; \
    (dst)[mf] = *(const bf16x8*)(atile + row * 128 + ((((kk) * 4 + lq) ^ (row & 7)) << 3)); } }
#define LOADA2(dst, kk) { _Pragma("unroll") for (int mf = 0; mf < 4; ++mf) { \
    int row = mf * 16 + l15; \
    (dst)[mf] = *(const bf16x8*)(h1 + row * 512 + (((kk) * 32 + lq * 8) ^ ((row & 7) << 3))); } }

    // ---- stage A-tile into LDS: issue ALL 16 corner loads, then lerp both halves ----
    if (SAMP) {
        const int li = tidx & 15;
        const int pr = tidx >> 4;           // 0..31
        const int co = li * 4;
        u32x4 d[2][8];
        float wxh[2], wyh[2], wzh[2];
        #pragma unroll
        for (int half = 0; half < 2; ++half) {
            int row = pr + 32 * half;       // 0..63
            int p   = m0 + row;
            int b   = p >> 16;
            float qx = qp[p * 3 + 0], qy = qp[p * 3 + 1], qz = qp[p * 3 + 2];
            float x = fminf(fmaxf(qx * 63.0f, 0.0f), 63.0f);
            float y = fminf(fmaxf(qy * 63.0f, 0.0f), 63.0f);
            float z = fminf(fmaxf(qz * 63.0f, 0.0f), 63.0f);
            int x0 = (int)floorf(x), y0 = (int)floorf(y), z0 = (int)floorf(z);
            int x1 = min(x0 + 1, 63), y1 = min(y0 + 1, 63), z1 = min(z0 + 1, 63);
            wxh[half] = x - (float)x0; wyh[half] = y - (float)y0; wzh[half] = z - (float)z0;
            const u32* fb = (const u32*)featT + ((size_t)b << 24);
            int zy00 = z0 * 4096 + y0 * 64, zy01 = z0 * 4096 + y1 * 64;
            int zy10 = z1 * 4096 + y0 * 64, zy11 = z1 * 4096 + y1 * 64;
            d[half][0] = *(const u32x4*)(fb + (size_t)(zy00 + x0) * 64 + co);
            d[half][1] = *(const u32x4*)(fb + (size_t)(zy00 + x1) * 64 + co);
            d[half][2] = *(const u32x4*)(fb + (size_t)(zy01 + x0) * 64 + co);
            d[half][3] = *(const u32x4*)(fb + (size_t)(zy01 + x1) * 64 + co);
            d[half][4] = *(const u32x4*)(fb + (size_t)(zy10 + x0) * 64 + co);
            d[half][5] = *(const u32x4*)(fb + (size_t)(zy10 + x1) * 64 + co);
            d[half][6] = *(const u32x4*)(fb + (size_t)(zy11 + x0) * 64 + co);
            d[half][7] = *(const u32x4*)(fb + (size_t)(zy11 + x1) * 64 + co);
        }
        #pragma unroll
        for (int half = 0; half < 2; ++half) {
            float wx = wxh[half], wy = wyh[half], wz = wzh[half];
            float omx = 1.0f - wx, omy = 1.0f - wy, omz = 1.0f - wz;
            int row = pr + 32 * half;
            u32x4 o;
            #pragma unroll
            for (int j = 0; j < 4; ++j) {
                float c00 = bflo(d[half][0][j]) * omx + bflo(d[half][1][j]) * wx;
                float c01 = bflo(d[half][2][j]) * omx + bflo(d[half][3][j]) * wx;
                float c10 = bflo(d[half][4][j]) * omx + bflo(d[half][5][j]) * wx;
                float c11 = bflo(d[half][6][j]) * omx + bflo(d[half][7][j]) * wx;
                float rl  = (c00 * omy + c01 * wy) * omz + (c10 * omy + c11 * wy) * wz;
                float e00 = bfhi(d[half][0][j]) * omx + bfhi(d[half][1][j]) * wx;
                float e01 = bfhi(d[half][2][j]) * omx + bfhi(d[half][3][j]) * wx;
                float e10 = bfhi(d[half][4][j]) * omx + bfhi(d[half][5][j]) * wx;
                float e11 = bfhi(d[half][6][j]) * omx + bfhi(d[half][7][j]) * wx;
                float rh  = (e00 * omy + e01 * wy) * omz + (e10 * omy + e11 * wy) * wz;
                o[j] = (u32)f2bf(rl) | ((u32)f2bf(rh) << 16);
            }
            *(u32x4*)(atile + row * 128 + ((li ^ (row & 7)) << 3)) = o;
        }
    } else {
        #pragma unroll
        for (int r2 = 0; r2 < 2; ++r2) {
            int idx = tidx + 512 * r2;      // 0..1023
            int row = idx >> 4, ch = idx & 15;
            u32x4 v = *(const u32x4*)(feats + (size_t)(m0 + row) * 128 + ch * 8);
            *(u32x4*)(atile + row * 128 + ((ch ^ (row & 7)) << 3)) = v;
        }
    }

    // prefetch GEMM1's first B panel under the barrier
    bf16x8 bv[2][4];
    LOADB1(bv[0], 0);
    __syncthreads();

    // ---- GEMM1: A(64x128 LDS) @ W1 panel(128x64), B 2-deep pipelined ----
    f32x4 acc[4][4];
    #pragma unroll
    for (int i = 0; i < 4; ++i)
        #pragma unroll
        for (int j = 0; j < 4; ++j) acc[i][j] = (f32x4){0.f, 0.f, 0.f, 0.f};
    bf16x8 pb[2][4];
    {
        #pragma unroll
        for (int kk = 0; kk < 4; ++kk) {
            const int cur = kk & 1, nxt = cur ^ 1;
            if (kk < 3) LOADB1(bv[nxt], kk + 1);
            if (kk == 3) LOADB2(pb[0], 0);   // W2 panel 0 overlaps last MFMA cluster + BN1
            bf16x8 av[4];
            LDSA(av, kk);
            __builtin_amdgcn_s_setprio(1);
            #pragma unroll
            for (int mf = 0; mf < 4; ++mf)
                #pragma unroll
                for (int nf = 0; nf < 4; ++nf)
                    acc[mf][nf] = __builtin_amdgcn_mfma_f32_16x16x32_bf16(av[mf], bv[cur][nf], acc[mf][nf], 0, 0, 0);
            __builtin_amdgcn_s_setprio(0);
        }
    }
    __syncthreads();   // atile readers done before BN1 overwrites h1

    // ---- BN1 + ReLU -> h1 (XOR-swizzled 16B chunks) ----
    {
        float s1v[4], t1v[4];
        #pragma unroll
        for (int nf = 0; nf < 4; ++nf) {
            int col = n0 + nf * 16 + l15;
            s1v[nf] = s1[col]; t1v[nf] = t1[col];
        }
        #pragma unroll
        for (int mf = 0; mf < 4; ++mf)
            #pragma unroll
            for (int nf = 0; nf < 4; ++nf) {
                int col = n0 + nf * 16 + l15;
                #pragma unroll
                for (int i = 0; i < 4; ++i) {
                    int row = mf * 16 + lq * 4 + i;
                    float v = fmaxf(acc[mf][nf][i] * s1v[nf] + t1v[nf], 0.0f);
                    h1[row * 512 + (col ^ ((row & 7) << 3))] = f2bf(v);
                }
            }
    }
    __syncthreads();

    // ---- GEMM2: h1(64x512) @ W2 panel(512x64), 16 k-steps, B 2-deep pipelined ----
    f32x4 acc2[4][4];
    #pragma unroll
    for (int i = 0; i < 4; ++i)
        #pragma unroll
        for (int j = 0; j < 4; ++j) acc2[i][j] = (f32x4){0.f, 0.f, 0.f, 0.f};
    {
        #pragma unroll
        for (int kk = 0; kk < 16; ++kk) {
            const int cur = kk & 1, nxt = cur ^ 1;
            if (kk < 15) LOADB2(pb[nxt], kk + 1);
            bf16x8 a2[4];
            LOADA2(a2, kk);
            __builtin_amdgcn_s_setprio(1);
            #pragma unroll
            for (int mf = 0; mf < 4; ++mf)
                #pragma unroll
                for (int nf = 0; nf < 4; ++nf)
                    acc2[mf][nf] = __builtin_amdgcn_mfma_f32_16x16x32_bf16(a2[mf], pb[cur][nf], acc2[mf][nf], 0, 0, 0);
            __builtin_amdgcn_s_setprio(0);
        }
    }

    // ---- BN2 + ReLU + partial dot with W3 (fp32), reduce 16 col-lanes ----
    float part[16];
    #pragma unroll
    for (int i = 0; i < 16; ++i) part[i] = 0.f;
    {
        float s2v[4], t2v[4], w3v[4];
        #pragma unroll
        for (int nf = 0; nf < 4; ++nf) {
            int col = n0 + nf * 16 + l15;
            s2v[nf] = s2[col]; t2v[nf] = t2[col]; w3v[nf] = W3[col];
        }
        #pragma unroll
        for (int mf = 0; mf < 4; ++mf)
            #pragma unroll
            for (int nf = 0; nf < 4; ++nf)
                #pragma unroll
                for (int i = 0; i < 4; ++i) {
                    float h = fmaxf(acc2[mf][nf][i] * s2v[nf] + t2v[nf], 0.0f);
                    part[mf * 4 + i] += h * w3v[nf];
                }
    }
    #pragma unroll
    for (int off = 1; off < 16; off <<= 1)
        #pragma unroll
        for (int i = 0; i < 16; ++i) part[i] += __shfl_xor(part[i], off, 64);

    if (l15 == 0) {
        #pragma unroll
        for (int mf = 0; mf < 4; ++mf)
            #pragma unroll
            for (int i = 0; i < 4; ++i)
                outb[w * 64 + mf * 16 + lq * 4 + i] = part[mf * 4 + i];
    }
    __syncthreads();
    if (tidx < 64) {
        float r = b3[0];
        #pragma unroll
        for (int ww = 0; ww < 8; ++ww) r += outb[ww * 64 + tidx];
        out[m0 + tidx] = r;
    }
#undef LOADB1
#undef LOADB2
#undef LDSA
#undef LOADA2
}

// ---------------- fallback scattered sampler (if ws too small for featT) ----------------
__global__ void sample_kernel(const float* __restrict__ feat,
                              const float* __restrict__ qp,
                              u16* __restrict__ fo)
{
    int tid = blockIdx.x * 256 + threadIdx.x;
    int p = tid >> 7;
    int c = tid & 127;
    int b = p >> 16;

    float qx = qp[p * 3 + 0], qy = qp[p * 3 + 1], qz = qp[p * 3 + 2];
    float x = fminf(fmaxf(qx * 63.0f, 0.0f), 63.0f);
    float y = fminf(fmaxf(qy * 63.0f, 0.0f), 63.0f);
    float z = fminf(fmaxf(qz * 63.0f, 0.0f), 63.0f);
    int x0 = (int)floorf(x), y0 = (int)floorf(y), z0 = (int)floorf(z);
    int x1 = min(x0 + 1, 63), y1 = min(y0 + 1, 63), z1 = min(z0 + 1, 63);
    float wx = x - (float)x0, wy = y - (float)y0, wz = z - (float)z0;

    const float* fb = feat + ((size_t)(b * NC + c) << 18);
    int zy00 = z0 * 4096 + y0 * 64, zy01 = z0 * 4096 + y1 * 64;
    int zy10 = z1 * 4096 + y0 * 64, zy11 = z1 * 4096 + y1 * 64;
    float f000 = fb[zy00 + x0], f001 = fb[zy00 + x1];
    float f010 = fb[zy01 + x0], f011 = fb[zy01 + x1];
    float f100 = fb[zy10 + x0], f101 = fb[zy10 + x1];
    float f110 = fb[zy11 + x0], f111 = fb[zy11 + x1];

    float omx = 1.0f - wx;
    float c00 = f000 * omx + f001 * wx;
    float c01 = f010 * omx + f011 * wx;
    float c10 = f100 * omx + f101 * wx;
    float c11 = f110 * omx + f111 * wx;
    float omy = 1.0f - wy;
    float c0 = c00 * omy + c01 * wy;
    float c1 = c10 * omy + c11 * wy;
    float v  = c0 * (1.0f - wz) + c1 * wz;
    fo[(size_t)p * 128 + c] = f2bf(v);
}

extern "C" void kernel_launch(void* const* d_in, const int* in_sizes, int n_in,
                              void* d_out, int out_size, void* d_ws, size_t ws_size,
                              hipStream_t stream)
{
    const float* feat = (const float*)d_in[0];
    const float* qp   = (const float*)d_in[1];
    const float* W1   = (const float*)d_in[2];
    const float* b1   = (const float*)d_in[3];
    const float* g1   = (const float*)d_in[4];
    const float* be1  = (const float*)d_in[5];
    const float* m1   = (const float*)d_in[6];
    const float* v1   = (const float*)d_in[7];
    const float* W2   = (const float*)d_in[8];
    const float* b2   = (const float*)d_in[9];
    const float* g2   = (const float*)d_in[10];
    const float* be2  = (const float*)d_in[11];
    const float* m2   = (const float*)d_in[12];
    const float* v2   = (const float*)d_in[13];
    const float* W3   = (const float*)d_in[14];
    const float* b3   = (const float*)d_in[15];

    char* ws = (char*)d_ws;
    u16*   W1p   = (u16*)(ws);                    // 131072 B
    u16*   W2p   = (u16*)(ws + 131072);           // 524288 B
    float* s1    = (float*)(ws + 655360);
    float* t1    = (float*)(ws + 657408);
    float* s2    = (float*)(ws + 659456);
    float* t2    = (float*)(ws + 661504);
    u16*   feats = (u16*)(ws + 663552);           // 33554432 B (fallback only)
    u16*   featT = (u16*)(ws + 663552 + 33554432);// 134217728 B
    const size_t needed = 663552 + 33554432 + 134217728;

    if (ws_size >= needed) {
        // transpose + prep fused into one launch (prep = tail 128 blocks)
        transpose_kernel<<<16384 + 128, 256, 0, stream>>>(
            feat, featT, W1, W2, b1, g1, be1, m1, v1, b2, g2, be2, m2, v2,
            W1p, W2p, s1, t1, s2, t2);
        fused_kernel<true><<<NTILE, 512, 0, stream>>>(featT, feats, qp, W1p, W2p,
                                                      s1, t1, s2, t2, W3, b3, (float*)d_out);
    } else {
        prep_kernel<<<128, 256, 0, stream>>>(W1, W2, b1, g1, be1, m1, v1,
                                             b2, g2, be2, m2, v2,
                                             W1p, W2p, s1, t1, s2, t2);
        sample_kernel<<<(MTOT * 128) / 256, 256, 0, stream>>>(feat, qp, feats);
        fused_kernel<false><<<NTILE, 512, 0, stream>>>(featT, feats, qp, W1p, W2p,
                                                       s1, t1, s2, t2, W3, b3, (float*)d_out);
    }
}

// Round 9
// 189.122 us; speedup vs baseline: 1.0157x; 1.0157x over previous
//
#include <hip/hip_runtime.h>
#include <hip/hip_bf16.h>

using bf16x8 = __attribute__((ext_vector_type(8))) short;
using f32x4  = __attribute__((ext_vector_type(4))) float;
using u32x4  = __attribute__((ext_vector_type(4))) unsigned int;
typedef unsigned short u16;
typedef unsigned int u32;

#define NB    2
#define NC    128
#define NPTS  65536
#define MTOT  (NB*NPTS)     // 131072
#define NTILE2 (MTOT/128)   // 1024 blocks, 128 points each

// round-to-nearest-even fp32 -> bf16 (bit pattern)
static __device__ __forceinline__ u16 f2bf(float f) {
    u32 u = __float_as_uint(f);
    u32 r = (u + 0x7FFFu + ((u >> 16) & 1u)) >> 16;
    return (u16)r;
}
static __device__ __forceinline__ float bflo(u32 d) { return __uint_as_float(d << 16); }
static __device__ __forceinline__ float bfhi(u32 d) { return __uint_as_float(d & 0xFFFF0000u); }

// ---------------- prep body: pack weights fragment-major (8 x 64-col panels) ----------------
static __device__ __forceinline__ void prep_body(
    int id,
    const float* __restrict__ W1, const float* __restrict__ W2,
    const float* __restrict__ b1, const float* __restrict__ g1, const float* __restrict__ be1,
    const float* __restrict__ m1, const float* __restrict__ v1,
    const float* __restrict__ b2, const float* __restrict__ g2, const float* __restrict__ be2,
    const float* __restrict__ m2, const float* __restrict__ v2,
    u16* __restrict__ W1p, u16* __restrict__ W2p,
    float* __restrict__ s1, float* __restrict__ t1,
    float* __restrict__ s2, float* __restrict__ t2)
{
    {   // W2p
        int l = id & 63, nf = (id >> 6) & 3, kk = (id >> 8) & 15, w = id >> 12;
        int n  = w * 64 + nf * 16 + (l & 15);
        int c0 = kk * 32 + (l >> 4) * 8;
        #pragma unroll
        for (int j = 0; j < 8; ++j)
            W2p[id * 8 + j] = f2bf(W2[(size_t)(c0 + j) * 512 + n]);
    }
    if (id < 8192) {   // W1p
        int l = id & 63, nf = (id >> 6) & 3, kk = (id >> 8) & 3, w = id >> 10;
        int n  = w * 64 + nf * 16 + (l & 15);
        int c0 = kk * 32 + (l >> 4) * 8;
        #pragma unroll
        for (int j = 0; j < 8; ++j)
            W1p[id * 8 + j] = f2bf(W1[(size_t)(c0 + j) * 512 + n]);
    }
    if (id < 512) {
        float s = g1[id] * rsqrtf(v1[id] + 1e-5f);
        s1[id] = s;
        t1[id] = (b1[id] - m1[id]) * s + be1[id];
        float ss = g2[id] * rsqrtf(v2[id] + 1e-5f);
        s2[id] = ss;
        t2[id] = (b2[id] - m2[id]) * ss + be2[id];
    }
}

__global__ void prep_kernel(
    const float* __restrict__ W1, const float* __restrict__ W2,
    const float* __restrict__ b1, const float* __restrict__ g1, const float* __restrict__ be1,
    const float* __restrict__ m1, const float* __restrict__ v1,
    const float* __restrict__ b2, const float* __restrict__ g2, const float* __restrict__ be2,
    const float* __restrict__ m2, const float* __restrict__ v2,
    u16* __restrict__ W1p, u16* __restrict__ W2p,
    float* __restrict__ s1, float* __restrict__ t1,
    float* __restrict__ s2, float* __restrict__ t2)
{
    prep_body(blockIdx.x * 256 + threadIdx.x, W1, W2, b1, g1, be1, m1, v1,
              b2, g2, be2, m2, v2, W1p, W2p, s1, t1, s2, t2);
}

// ---------------- volume transpose (+ prep in tail blocks) ----------------
__global__ __launch_bounds__(256) void transpose_kernel(
    const float* __restrict__ feat, u16* __restrict__ featT,
    const float* __restrict__ W1, const float* __restrict__ W2,
    const float* __restrict__ b1, const float* __restrict__ g1, const float* __restrict__ be1,
    const float* __restrict__ m1, const float* __restrict__ v1,
    const float* __restrict__ b2, const float* __restrict__ g2, const float* __restrict__ be2,
    const float* __restrict__ m2, const float* __restrict__ v2,
    u16* __restrict__ W1p, u16* __restrict__ W2p,
    float* __restrict__ s1, float* __restrict__ t1,
    float* __restrict__ s2, float* __restrict__ t2)
{
    __shared__ float tile[128][33];
    int blk = blockIdx.x;               // 0..16511
    if (blk >= 16384) {                 // prep tail
        prep_body((blk - 16384) * 256 + threadIdx.x, W1, W2, b1, g1, be1, m1, v1,
                  b2, g2, be2, m2, v2, W1p, W2p, s1, t1, s2, t2);
        return;
    }
    int b   = blk >> 13;
    int v0  = (blk & 8191) << 5;        // 32 voxels per block
    int t   = threadIdx.x;
    const float* fb = feat + ((size_t)b << 25) + v0;
    int c_l = t >> 3, f4 = t & 7;
    #pragma unroll
    for (int r = 0; r < 4; ++r) {
        int c = c_l + 32 * r;
        float4 v = *(const float4*)(fb + ((size_t)c << 18) + f4 * 4);
        tile[c][f4 * 4 + 0] = v.x;
        tile[c][f4 * 4 + 1] = v.y;
        tile[c][f4 * 4 + 2] = v.z;
        tile[c][f4 * 4 + 3] = v.w;
    }
    __syncthreads();
    u32* outp = (u32*)(featT + (((size_t)b << 18) + v0) * 128);
    #pragma unroll
    for (int r = 0; r < 2; ++r) {
        int idx = t + 256 * r;          // 0..511
        int v   = idx >> 4;             // voxel 0..31
        int c4  = idx & 15;             // 8-channel group
        u32x4 o;
        #pragma unroll
        for (int k = 0; k < 4; ++k) {
            float lo = tile[8 * c4 + 2 * k + 0][v];
            float hi = tile[8 * c4 + 2 * k + 1][v];
            o[k] = (u32)f2bf(lo) | ((u32)f2bf(hi) << 16);
        }
        *(u32x4*)(outp + (size_t)v * 64 + c4 * 4) = o;
    }
}

// ---------------- fused sample + MLP: 1024 threads / 16 waves (2M x 8N), 128 points/block ----------------
// Gather is SEQUENTIAL per-half (low live-set, no spill); pb prefetch after GEMM1 (R6 placement).
template<bool SAMP>
__global__ __launch_bounds__(1024, 4) void fused_kernel(
    const u16* __restrict__ featT, const u16* __restrict__ feats,
    const float* __restrict__ qp,
    const u16* __restrict__ W1p, const u16* __restrict__ W2p,
    const float* __restrict__ s1, const float* __restrict__ t1,
    const float* __restrict__ s2, const float* __restrict__ t2,
    const float* __restrict__ W3, const float* __restrict__ b3,
    float* __restrict__ out)
{
    __shared__ u16 h1[128 * 512];     // 128 KiB; first 32 KiB doubles as the A-tile
    __shared__ float outb[1024];      // 4 KiB
    u16* atile = h1;                  // [128 rows][16 chunks of 8 bf16], chunk ^= (row&7)

    const int tidx = threadIdx.x;
    const int w    = tidx >> 6;       // 0..15
    const int wr   = w >> 3;          // 0..1  (M half)
    const int wc   = w & 7;           // 0..7  (N panel)
    const int l    = tidx & 63;
    const int l15  = l & 15;
    const int lq   = l >> 4;
    const int m0   = blockIdx.x * 128;
    const int mr0  = wr * 64;
    const int n0   = wc * 64;

    const u16* B1 = W1p + (size_t)(wc * 4)  * 4 * 512;
    const u16* B2 = W2p + (size_t)(wc * 16) * 4 * 512;

#define LOADB1(dst, kk) { _Pragma("unroll") for (int nf = 0; nf < 4; ++nf) \
    (dst)[nf] = *(const bf16x8*)(B1 + ((kk) * 4 + nf) * 512 + l * 8); }
#define LOADB2(dst, kk) { _Pragma("unroll") for (int nf = 0; nf < 4; ++nf) \
    (dst)[nf] = *(const bf16x8*)(B2 + ((kk) * 4 + nf) * 512 + l * 8); }
#define LDSA(dst, kk) { _Pragma("unroll") for (int mf = 0; mf < 4; ++mf) { \
    int row = mr0 + mf * 16 + l15; \
    (dst)[mf] = *(const bf16x8*)(atile + row * 128 + ((((kk) * 4 + lq) ^ (row & 7)) << 3)); } }
#define LOADA2(dst, kk) { _Pragma("unroll") for (int mf = 0; mf < 4; ++mf) { \
    int row = mr0 + mf * 16 + l15; \
    (dst)[mf] = *(const bf16x8*)(h1 + row * 512 + (((kk) * 32 + lq * 8) ^ ((row & 7) << 3))); } }

    // ---- stage A-tile into LDS: per-half sequential gather (small live-set) ----
    if (SAMP) {
        const int li = tidx & 15;
        const int pr = tidx >> 4;           // 0..63
        const int co = li * 4;
        #pragma unroll
        for (int half = 0; half < 2; ++half) {
            int row = pr + 64 * half;       // 0..127
            int p   = m0 + row;
            int b   = p >> 16;
            float qx = qp[p * 3 + 0], qy = qp[p * 3 + 1], qz = qp[p * 3 + 2];
            float x = fminf(fmaxf(qx * 63.0f, 0.0f), 63.0f);
            float y = fminf(fmaxf(qy * 63.0f, 0.0f), 63.0f);
            float z = fminf(fmaxf(qz * 63.0f, 0.0f), 63.0f);
            int x0 = (int)floorf(x), y0 = (int)floorf(y), z0 = (int)floorf(z);
            int x1 = min(x0 + 1, 63), y1 = min(y0 + 1, 63), z1 = min(z0 + 1, 63);
            float wx = x - (float)x0, wy = y - (float)y0, wz = z - (float)z0;
            const u32* fb = (const u32*)featT + ((size_t)b << 24);
            int zy00 = z0 * 4096 + y0 * 64, zy01 = z0 * 4096 + y1 * 64;
            int zy10 = z1 * 4096 + y0 * 64, zy11 = z1 * 4096 + y1 * 64;
            u32x4 d000 = *(const u32x4*)(fb + (size_t)(zy00 + x0) * 64 + co);
            u32x4 d001 = *(const u32x4*)(fb + (size_t)(zy00 + x1) * 64 + co);
            u32x4 d010 = *(const u32x4*)(fb + (size_t)(zy01 + x0) * 64 + co);
            u32x4 d011 = *(const u32x4*)(fb + (size_t)(zy01 + x1) * 64 + co);
            u32x4 d100 = *(const u32x4*)(fb + (size_t)(zy10 + x0) * 64 + co);
            u32x4 d101 = *(const u32x4*)(fb + (size_t)(zy10 + x1) * 64 + co);
            u32x4 d110 = *(const u32x4*)(fb + (size_t)(zy11 + x0) * 64 + co);
            u32x4 d111 = *(const u32x4*)(fb + (size_t)(zy11 + x1) * 64 + co);

            float omx = 1.0f - wx, omy = 1.0f - wy, omz = 1.0f - wz;
            u32x4 o;
            #pragma unroll
            for (int j = 0; j < 4; ++j) {
                float c00 = bflo(d000[j]) * omx + bflo(d001[j]) * wx;
                float c01 = bflo(d010[j]) * omx + bflo(d011[j]) * wx;
                float c10 = bflo(d100[j]) * omx + bflo(d101[j]) * wx;
                float c11 = bflo(d110[j]) * omx + bflo(d111[j]) * wx;
                float rl  = (c00 * omy + c01 * wy) * omz + (c10 * omy + c11 * wy) * wz;
                float e00 = bfhi(d000[j]) * omx + bfhi(d001[j]) * wx;
                float e01 = bfhi(d010[j]) * omx + bfhi(d011[j]) * wx;
                float e10 = bfhi(d100[j]) * omx + bfhi(d101[j]) * wx;
                float e11 = bfhi(d110[j]) * omx + bfhi(d111[j]) * wx;
                float rh  = (e00 * omy + e01 * wy) * omz + (e10 * omy + e11 * wy) * wz;
                o[j] = (u32)f2bf(rl) | ((u32)f2bf(rh) << 16);
            }
            *(u32x4*)(atile + row * 128 + ((li ^ (row & 7)) << 3)) = o;
        }
    } else {
        #pragma unroll
        for (int r2 = 0; r2 < 2; ++r2) {
            int idx = tidx + 1024 * r2;     // 0..2047
            int row = idx >> 4, ch = idx & 15;
            u32x4 v = *(const u32x4*)(feats + (size_t)(m0 + row) * 128 + ch * 8);
            *(u32x4*)(atile + row * 128 + ((ch ^ (row & 7)) << 3)) = v;
        }
    }

    // prefetch GEMM1's first B panel under the barrier
    bf16x8 bv[2][4];
    LOADB1(bv[0], 0);
    __syncthreads();

    // ---- GEMM1: A(128x128 LDS) @ W1 panel(128x64), B 2-deep pipelined ----
    f32x4 acc[4][4];
    #pragma unroll
    for (int i = 0; i < 4; ++i)
        #pragma unroll
        for (int j = 0; j < 4; ++j) acc[i][j] = (f32x4){0.f, 0.f, 0.f, 0.f};
    {
        #pragma unroll
        for (int kk = 0; kk < 4; ++kk) {
            const int cur = kk & 1, nxt = cur ^ 1;
            if (kk < 3) LOADB1(bv[nxt], kk + 1);
            bf16x8 av[4];
            LDSA(av, kk);
            __builtin_amdgcn_s_setprio(1);
            #pragma unroll
            for (int mf = 0; mf < 4; ++mf)
                #pragma unroll
                for (int nf = 0; nf < 4; ++nf)
                    acc[mf][nf] = __builtin_amdgcn_mfma_f32_16x16x32_bf16(av[mf], bv[cur][nf], acc[mf][nf], 0, 0, 0);
            __builtin_amdgcn_s_setprio(0);
        }
    }

    // prefetch GEMM2's first B panel, then guard atile before overwriting h1
    bf16x8 pb[2][4];
    LOADB2(pb[0], 0);
    __syncthreads();

    // ---- BN1 + ReLU -> h1 (XOR-swizzled 16B chunks) ----
    {
        float s1v[4], t1v[4];
        #pragma unroll
        for (int nf = 0; nf < 4; ++nf) {
            int col = n0 + nf * 16 + l15;
            s1v[nf] = s1[col]; t1v[nf] = t1[col];
        }
        #pragma unroll
        for (int mf = 0; mf < 4; ++mf)
            #pragma unroll
            for (int nf = 0; nf < 4; ++nf) {
                int col = n0 + nf * 16 + l15;
                #pragma unroll
                for (int i = 0; i < 4; ++i) {
                    int row = mr0 + mf * 16 + lq * 4 + i;
                    float v = fmaxf(acc[mf][nf][i] * s1v[nf] + t1v[nf], 0.0f);
                    h1[row * 512 + (col ^ ((row & 7) << 3))] = f2bf(v);
                }
            }
    }
    __syncthreads();

    // ---- GEMM2: h1(128x512) @ W2 panel(512x64), 16 k-steps, B 2-deep pipelined ----
    f32x4 acc2[4][4];
    #pragma unroll
    for (int i = 0; i < 4; ++i)
        #pragma unroll
        for (int j = 0; j < 4; ++j) acc2[i][j] = (f32x4){0.f, 0.f, 0.f, 0.f};
    {
        #pragma unroll
        for (int kk = 0; kk < 16; ++kk) {
            const int cur = kk & 1, nxt = cur ^ 1;
            if (kk < 15) LOADB2(pb[nxt], kk + 1);
            bf16x8 a2[4];
            LOADA2(a2, kk);
            __builtin_amdgcn_s_setprio(1);
            #pragma unroll
            for (int mf = 0; mf < 4; ++mf)
                #pragma unroll
                for (int nf = 0; nf < 4; ++nf)
                    acc2[mf][nf] = __builtin_amdgcn_mfma_f32_16x16x32_bf16(a2[mf], pb[cur][nf], acc2[mf][nf], 0, 0, 0);
            __builtin_amdgcn_s_setprio(0);
        }
    }

    // ---- BN2 + ReLU + partial dot with W3 (fp32), reduce 16 col-lanes ----
    float part[16];
    #pragma unroll
    for (int i = 0; i < 16; ++i) part[i] = 0.f;
    {
        float s2v[4], t2v[4], w3v[4];
        #pragma unroll
        for (int nf = 0; nf < 4; ++nf) {
            int col = n0 + nf * 16 + l15;
            s2v[nf] = s2[col]; t2v[nf] = t2[col]; w3v[nf] = W3[col];
        }
        #pragma unroll
        for (int mf = 0; mf < 4; ++mf)
            #pragma unroll
            for (int nf = 0; nf < 4; ++nf)
                #pragma unroll
                for (int i = 0; i < 4; ++i) {
                    float h = fmaxf(acc2[mf][nf][i] * s2v[nf] + t2v[nf], 0.0f);
                    part[mf * 4 + i] += h * w3v[nf];
                }
    }
    #pragma unroll
    for (int off = 1; off < 16; off <<= 1)
        #pragma unroll
        for (int i = 0; i < 16; ++i) part[i] += __shfl_xor(part[i], off, 64);

    if (l15 == 0) {
        #pragma unroll
        for (int mf = 0; mf < 4; ++mf)
            #pragma unroll
            for (int i = 0; i < 4; ++i)
                outb[w * 64 + mf * 16 + lq * 4 + i] = part[mf * 4 + i];
    }
    __syncthreads();
    if (tidx < 128) {
        int r = tidx >> 6, m = tidx & 63;
        float s = b3[0];
        #pragma unroll
        for (int c = 0; c < 8; ++c) s += outb[(r * 8 + c) * 64 + m];
        out[m0 + tidx] = s;
    }
#undef LOADB1
#undef LOADB2
#undef LDSA
#undef LOADA2
}

// ---------------- fallback scattered sampler (if ws too small for featT) ----------------
__global__ void sample_kernel(const float* __restrict__ feat,
                              const float* __restrict__ qp,
                              u16* __restrict__ fo)
{
    int tid = blockIdx.x * 256 + threadIdx.x;
    int p = tid >> 7;
    int c = tid & 127;
    int b = p >> 16;

    float qx = qp[p * 3 + 0], qy = qp[p * 3 + 1], qz = qp[p * 3 + 2];
    float x = fminf(fmaxf(qx * 63.0f, 0.0f), 63.0f);
    float y = fminf(fmaxf(qy * 63.0f, 0.0f), 63.0f);
    float z = fminf(fmaxf(qz * 63.0f, 0.0f), 63.0f);
    int x0 = (int)floorf(x), y0 = (int)floorf(y), z0 = (int)floorf(z);
    int x1 = min(x0 + 1, 63), y1 = min(y0 + 1, 63), z1 = min(z0 + 1, 63);
    float wx = x - (float)x0, wy = y - (float)y0, wz = z - (float)z0;

    const float* fb = feat + ((size_t)(b * NC + c) << 18);
    int zy00 = z0 * 4096 + y0 * 64, zy01 = z0 * 4096 + y1 * 64;
    int zy10 = z1 * 4096 + y0 * 64, zy11 = z1 * 4096 + y1 * 64;
    float f000 = fb[zy00 + x0], f001 = fb[zy00 + x1];
    float f010 = fb[zy01 + x0], f011 = fb[zy01 + x1];
    float f100 = fb[zy10 + x0], f101 = fb[zy10 + x1];
    float f110 = fb[zy11 + x0], f111 = fb[zy11 + x1];

    float omx = 1.0f - wx;
    float c00 = f000 * omx + f001 * wx;
    float c01 = f010 * omx + f011 * wx;
    float c10 = f100 * omx + f101 * wx;
    float c11 = f110 * omx + f111 * wx;
    float omy = 1.0f - wy;
    float c0 = c00 * omy + c01 * wy;
    float c1 = c10 * omy + c11 * wy;
    float v  = c0 * (1.0f - wz) + c1 * wz;
    fo[(size_t)p * 128 + c] = f2bf(v);
}

extern "C" void kernel_launch(void* const* d_in, const int* in_sizes, int n_in,
                              void* d_out, int out_size, void* d_ws, size_t ws_size,
                              hipStream_t stream)
{
    const float* feat = (const float*)d_in[0];
    const float* qp   = (const float*)d_in[1];
    const float* W1   = (const float*)d_in[2];
    const float* b1   = (const float*)d_in[3];
    const float* g1   = (const float*)d_in[4];
    const float* be1  = (const float*)d_in[5];
    const float* m1   = (const float*)d_in[6];
    const float* v1   = (const float*)d_in[7];
    const float* W2   = (const float*)d_in[8];
    const float* b2   = (const float*)d_in[9];
    const float* g2   = (const float*)d_in[10];
    const float* be2  = (const float*)d_in[11];
    const float* m2   = (const float*)d_in[12];
    const float* v2   = (const float*)d_in[13];
    const float* W3   = (const float*)d_in[14];
    const float* b3   = (const float*)d_in[15];

    char* ws = (char*)d_ws;
    u16*   W1p   = (u16*)(ws);                    // 131072 B
    u16*   W2p   = (u16*)(ws + 131072);           // 524288 B
    float* s1    = (float*)(ws + 655360);
    float* t1    = (float*)(ws + 657408);
    float* s2    = (float*)(ws + 659456);
    float* t2    = (float*)(ws + 661504);
    u16*   feats = (u16*)(ws + 663552);           // 33554432 B (fallback only)
    u16*   featT = (u16*)(ws + 663552 + 33554432);// 134217728 B
    const size_t needed = 663552 + 33554432 + 134217728;

    if (ws_size >= needed) {
        transpose_kernel<<<16384 + 128, 256, 0, stream>>>(
            feat, featT, W1, W2, b1, g1, be1, m1, v1, b2, g2, be2, m2, v2,
            W1p, W2p, s1, t1, s2, t2);
        fused_kernel<true><<<NTILE2, 1024, 0, stream>>>(featT, feats, qp, W1p, W2p,
                                                        s1, t1, s2, t2, W3, b3, (float*)d_out);
    } else {
        prep_kernel<<<128, 256, 0, stream>>>(W1, W2, b1, g1, be1, m1, v1,
                                             b2, g2, be2, m2, v2,
                                             W1p, W2p, s1, t1, s2, t2);
        sample_kernel<<<(MTOT * 128) / 256, 256, 0, stream>>>(feat, qp, feats);
        fused_kernel<false><<<NTILE2, 1024, 0, stream>>>(featT, feats, qp, W1p, W2p,
                                                         s1, t1, s2, t2, W3, b3, (float*)d_out);
    }
}

// Round 10
// 173.210 us; speedup vs baseline: 1.1090x; 1.0919x over previous
//
#include <hip/hip_runtime.h>
#include <hip/hip_bf16.h>

using bf16x8 = __attribute__((ext_vector_type(8))) short;
using f32x4  = __attribute__((ext_vector_type(4))) float;
using u32x4  = __attribute__((ext_vector_type(4))) unsigned int;
typedef unsigned short u16;
typedef unsigned int u32;

#define NB    2
#define NC    128
#define NPTS  65536
#define MTOT  (NB*NPTS)     // 131072
#define NTILE (MTOT/64)     // 2048

// round-to-nearest-even fp32 -> bf16 (bit pattern)
static __device__ __forceinline__ u16 f2bf(float f) {
    u32 u = __float_as_uint(f);
    u32 r = (u + 0x7FFFu + ((u >> 16) & 1u)) >> 16;
    return (u16)r;
}
static __device__ __forceinline__ float bflo(u32 d) { return __uint_as_float(d << 16); }
static __device__ __forceinline__ float bfhi(u32 d) { return __uint_as_float(d & 0xFFFF0000u); }

// ---------------- prep body: pack weights fragment-major (8 x 64-col panels) ----------------
static __device__ __forceinline__ void prep_body(
    int id,
    const float* __restrict__ W1, const float* __restrict__ W2,
    const float* __restrict__ b1, const float* __restrict__ g1, const float* __restrict__ be1,
    const float* __restrict__ m1, const float* __restrict__ v1,
    const float* __restrict__ b2, const float* __restrict__ g2, const float* __restrict__ be2,
    const float* __restrict__ m2, const float* __restrict__ v2,
    u16* __restrict__ W1p, u16* __restrict__ W2p,
    float* __restrict__ s1, float* __restrict__ t1,
    float* __restrict__ s2, float* __restrict__ t2)
{
    {   // W2p
        int l = id & 63, nf = (id >> 6) & 3, kk = (id >> 8) & 15, w = id >> 12;
        int n  = w * 64 + nf * 16 + (l & 15);
        int c0 = kk * 32 + (l >> 4) * 8;
        #pragma unroll
        for (int j = 0; j < 8; ++j)
            W2p[id * 8 + j] = f2bf(W2[(size_t)(c0 + j) * 512 + n]);
    }
    if (id < 8192) {   // W1p
        int l = id & 63, nf = (id >> 6) & 3, kk = (id >> 8) & 3, w = id >> 10;
        int n  = w * 64 + nf * 16 + (l & 15);
        int c0 = kk * 32 + (l >> 4) * 8;
        #pragma unroll
        for (int j = 0; j < 8; ++j)
            W1p[id * 8 + j] = f2bf(W1[(size_t)(c0 + j) * 512 + n]);
    }
    if (id < 512) {
        float s = g1[id] * rsqrtf(v1[id] + 1e-5f);
        s1[id] = s;
        t1[id] = (b1[id] - m1[id]) * s + be1[id];
        float ss = g2[id] * rsqrtf(v2[id] + 1e-5f);
        s2[id] = ss;
        t2[id] = (b2[id] - m2[id]) * ss + be2[id];
    }
}

__global__ void prep_kernel(
    const float* __restrict__ W1, const float* __restrict__ W2,
    const float* __restrict__ b1, const float* __restrict__ g1, const float* __restrict__ be1,
    const float* __restrict__ m1, const float* __restrict__ v1,
    const float* __restrict__ b2, const float* __restrict__ g2, const float* __restrict__ be2,
    const float* __restrict__ m2, const float* __restrict__ v2,
    u16* __restrict__ W1p, u16* __restrict__ W2p,
    float* __restrict__ s1, float* __restrict__ t1,
    float* __restrict__ s2, float* __restrict__ t2)
{
    prep_body(blockIdx.x * 256 + threadIdx.x, W1, W2, b1, g1, be1, m1, v1,
              b2, g2, be2, m2, v2, W1p, W2p, s1, t1, s2, t2);
}

// ---------------- volume transpose (+ prep in tail blocks) ----------------
__global__ __launch_bounds__(256) void transpose_kernel(
    const float* __restrict__ feat, u16* __restrict__ featT,
    const float* __restrict__ W1, const float* __restrict__ W2,
    const float* __restrict__ b1, const float* __restrict__ g1, const float* __restrict__ be1,
    const float* __restrict__ m1, const float* __restrict__ v1,
    const float* __restrict__ b2, const float* __restrict__ g2, const float* __restrict__ be2,
    const float* __restrict__ m2, const float* __restrict__ v2,
    u16* __restrict__ W1p, u16* __restrict__ W2p,
    float* __restrict__ s1, float* __restrict__ t1,
    float* __restrict__ s2, float* __restrict__ t2)
{
    __shared__ float tile[128][33];
    int blk = blockIdx.x;               // 0..16511
    if (blk >= 16384) {                 // prep tail
        prep_body((blk - 16384) * 256 + threadIdx.x, W1, W2, b1, g1, be1, m1, v1,
                  b2, g2, be2, m2, v2, W1p, W2p, s1, t1, s2, t2);
        return;
    }
    int b   = blk >> 13;
    int v0  = (blk & 8191) << 5;        // 32 voxels per block
    int t   = threadIdx.x;
    const float* fb = feat + ((size_t)b << 25) + v0;
    int c_l = t >> 3, f4 = t & 7;
    #pragma unroll
    for (int r = 0; r < 4; ++r) {
        int c = c_l + 32 * r;
        float4 v = *(const float4*)(fb + ((size_t)c << 18) + f4 * 4);
        tile[c][f4 * 4 + 0] = v.x;
        tile[c][f4 * 4 + 1] = v.y;
        tile[c][f4 * 4 + 2] = v.z;
        tile[c][f4 * 4 + 3] = v.w;
    }
    __syncthreads();
    u32* outp = (u32*)(featT + (((size_t)b << 18) + v0) * 128);
    #pragma unroll
    for (int r = 0; r < 2; ++r) {
        int idx = t + 256 * r;          // 0..511
        int v   = idx >> 4;             // voxel 0..31
        int c4  = idx & 15;             // 8-channel group
        u32x4 o;
        #pragma unroll
        for (int k = 0; k < 4; ++k) {
            float lo = tile[8 * c4 + 2 * k + 0][v];
            float hi = tile[8 * c4 + 2 * k + 1][v];
            o[k] = (u32)f2bf(lo) | ((u32)f2bf(hi) << 16);
        }
        *(u32x4*)(outp + (size_t)v * 64 + c4 * 4) = o;
    }
}

// ---------------- fused sample + MLP: 512 threads / 8 waves, 64 points per block ----------------
// EXACT R6 structure (best known: 177 us). Sequential per-half gather, pb prefetch after GEMM1.
template<bool SAMP>
__global__ __launch_bounds__(512, 4) void fused_kernel(
    const u16* __restrict__ featT, const u16* __restrict__ feats,
    const float* __restrict__ qp,
    const u16* __restrict__ W1p, const u16* __restrict__ W2p,
    const float* __restrict__ s1, const float* __restrict__ t1,
    const float* __restrict__ s2, const float* __restrict__ t2,
    const float* __restrict__ W3, const float* __restrict__ b3,
    float* __restrict__ out)
{
    __shared__ u16 h1[64 * 512];      // 64 KiB; first 16 KiB doubles as the A-tile
    __shared__ float outb[512];       // 2 KiB
    u16* atile = h1;                  // [64 rows][16 chunks of 8 bf16], chunk ^= (row&7)

    const int tidx = threadIdx.x;
    const int w    = tidx >> 6;       // 0..7
    const int l    = tidx & 63;
    const int l15  = l & 15;
    const int lq   = l >> 4;
    const int m0   = blockIdx.x * 64;
    const int n0   = w * 64;

    const u16* B1 = W1p + (size_t)(w * 4)  * 4 * 512;
    const u16* B2 = W2p + (size_t)(w * 16) * 4 * 512;

#define LOADB1(dst, kk) { _Pragma("unroll") for (int nf = 0; nf < 4; ++nf) \
    (dst)[nf] = *(const bf16x8*)(B1 + ((kk) * 4 + nf) * 512 + l * 8); }
#define LOADB2(dst, kk) { _Pragma("unroll") for (int nf = 0; nf < 4; ++nf) \
    (dst)[nf] = *(const bf16x8*)(B2 + ((kk) * 4 + nf) * 512 + l * 8); }
#define LDSA(dst, kk) { _Pragma("unroll") for (int mf = 0; mf < 4; ++mf) { \
    int row = mf * 16 + l15; \
    (dst)[mf] = *(const bf16x8*)(atile + row * 128 + ((((kk) * 4 + lq) ^ (row & 7)) << 3)); } }
#define LOADA2(dst, kk) { _Pragma("unroll") for (int mf = 0; mf < 4; ++mf) { \
    int row = mf * 16 + l15; \
    (dst)[mf] = *(const bf16x8*)(h1 + row * 512 + (((kk) * 32 + lq * 8) ^ ((row & 7) << 3))); } }

    // ---- stage A-tile into LDS: sequential per-half gather (small live-set) ----
    if (SAMP) {
        const int li = tidx & 15;
        const int pr = tidx >> 4;           // 0..31
        const int co = li * 4;
        #pragma unroll
        for (int half = 0; half < 2; ++half) {
            int row = pr + 32 * half;       // 0..63
            int p   = m0 + row;
            int b   = p >> 16;
            float qx = qp[p * 3 + 0], qy = qp[p * 3 + 1], qz = qp[p * 3 + 2];
            float x = fminf(fmaxf(qx * 63.0f, 0.0f), 63.0f);
            float y = fminf(fmaxf(qy * 63.0f, 0.0f), 63.0f);
            float z = fminf(fmaxf(qz * 63.0f, 0.0f), 63.0f);
            int x0 = (int)floorf(x), y0 = (int)floorf(y), z0 = (int)floorf(z);
            int x1 = min(x0 + 1, 63), y1 = min(y0 + 1, 63), z1 = min(z0 + 1, 63);
            float wx = x - (float)x0, wy = y - (float)y0, wz = z - (float)z0;
            const u32* fb = (const u32*)featT + ((size_t)b << 24);
            int zy00 = z0 * 4096 + y0 * 64, zy01 = z0 * 4096 + y1 * 64;
            int zy10 = z1 * 4096 + y0 * 64, zy11 = z1 * 4096 + y1 * 64;
            u32x4 d000 = *(const u32x4*)(fb + (size_t)(zy00 + x0) * 64 + co);
            u32x4 d001 = *(const u32x4*)(fb + (size_t)(zy00 + x1) * 64 + co);
            u32x4 d010 = *(const u32x4*)(fb + (size_t)(zy01 + x0) * 64 + co);
            u32x4 d011 = *(const u32x4*)(fb + (size_t)(zy01 + x1) * 64 + co);
            u32x4 d100 = *(const u32x4*)(fb + (size_t)(zy10 + x0) * 64 + co);
            u32x4 d101 = *(const u32x4*)(fb + (size_t)(zy10 + x1) * 64 + co);
            u32x4 d110 = *(const u32x4*)(fb + (size_t)(zy11 + x0) * 64 + co);
            u32x4 d111 = *(const u32x4*)(fb + (size_t)(zy11 + x1) * 64 + co);

            float omx = 1.0f - wx, omy = 1.0f - wy, omz = 1.0f - wz;
            u32x4 o;
            #pragma unroll
            for (int j = 0; j < 4; ++j) {
                float c00 = bflo(d000[j]) * omx + bflo(d001[j]) * wx;
                float c01 = bflo(d010[j]) * omx + bflo(d011[j]) * wx;
                float c10 = bflo(d100[j]) * omx + bflo(d101[j]) * wx;
                float c11 = bflo(d110[j]) * omx + bflo(d111[j]) * wx;
                float rl  = (c00 * omy + c01 * wy) * omz + (c10 * omy + c11 * wy) * wz;
                float e00 = bfhi(d000[j]) * omx + bfhi(d001[j]) * wx;
                float e01 = bfhi(d010[j]) * omx + bfhi(d011[j]) * wx;
                float e10 = bfhi(d100[j]) * omx + bfhi(d101[j]) * wx;
                float e11 = bfhi(d110[j]) * omx + bfhi(d111[j]) * wx;
                float rh  = (e00 * omy + e01 * wy) * omz + (e10 * omy + e11 * wy) * wz;
                o[j] = (u32)f2bf(rl) | ((u32)f2bf(rh) << 16);
            }
            *(u32x4*)(atile + row * 128 + ((li ^ (row & 7)) << 3)) = o;
        }
    } else {
        #pragma unroll
        for (int r2 = 0; r2 < 2; ++r2) {
            int idx = tidx + 512 * r2;      // 0..1023
            int row = idx >> 4, ch = idx & 15;
            u32x4 v = *(const u32x4*)(feats + (size_t)(m0 + row) * 128 + ch * 8);
            *(u32x4*)(atile + row * 128 + ((ch ^ (row & 7)) << 3)) = v;
        }
    }

    // prefetch GEMM1's first B panel under the barrier
    bf16x8 bv[2][4];
    LOADB1(bv[0], 0);
    __syncthreads();

    // ---- GEMM1: A(64x128 LDS) @ W1 panel(128x64), B 2-deep pipelined ----
    f32x4 acc[4][4];
    #pragma unroll
    for (int i = 0; i < 4; ++i)
        #pragma unroll
        for (int j = 0; j < 4; ++j) acc[i][j] = (f32x4){0.f, 0.f, 0.f, 0.f};
    {
        #pragma unroll
        for (int kk = 0; kk < 4; ++kk) {
            const int cur = kk & 1, nxt = cur ^ 1;
            if (kk < 3) LOADB1(bv[nxt], kk + 1);
            bf16x8 av[4];
            LDSA(av, kk);
            __builtin_amdgcn_s_setprio(1);
            #pragma unroll
            for (int mf = 0; mf < 4; ++mf)
                #pragma unroll
                for (int nf = 0; nf < 4; ++nf)
                    acc[mf][nf] = __builtin_amdgcn_mfma_f32_16x16x32_bf16(av[mf], bv[cur][nf], acc[mf][nf], 0, 0, 0);
            __builtin_amdgcn_s_setprio(0);
        }
    }

    // prefetch GEMM2's first B panel, then guard atile before overwriting h1
    bf16x8 pb[2][4];
    LOADB2(pb[0], 0);
    __syncthreads();

    // ---- BN1 + ReLU -> h1 (XOR-swizzled 16B chunks) ----
    {
        float s1v[4], t1v[4];
        #pragma unroll
        for (int nf = 0; nf < 4; ++nf) {
            int col = n0 + nf * 16 + l15;
            s1v[nf] = s1[col]; t1v[nf] = t1[col];
        }
        #pragma unroll
        for (int mf = 0; mf < 4; ++mf)
            #pragma unroll
            for (int nf = 0; nf < 4; ++nf) {
                int col = n0 + nf * 16 + l15;
                #pragma unroll
                for (int i = 0; i < 4; ++i) {
                    int row = mf * 16 + lq * 4 + i;
                    float v = fmaxf(acc[mf][nf][i] * s1v[nf] + t1v[nf], 0.0f);
                    h1[row * 512 + (col ^ ((row & 7) << 3))] = f2bf(v);
                }
            }
    }
    __syncthreads();

    // ---- GEMM2: h1(64x512) @ W2 panel(512x64), 16 k-steps, B 2-deep pipelined ----
    f32x4 acc2[4][4];
    #pragma unroll
    for (int i = 0; i < 4; ++i)
        #pragma unroll
        for (int j = 0; j < 4; ++j) acc2[i][j] = (f32x4){0.f, 0.f, 0.f, 0.f};
    {
        #pragma unroll
        for (int kk = 0; kk < 16; ++kk) {
            const int cur = kk & 1, nxt = cur ^ 1;
            if (kk < 15) LOADB2(pb[nxt], kk + 1);
            bf16x8 a2[4];
            LOADA2(a2, kk);
            __builtin_amdgcn_s_setprio(1);
            #pragma unroll
            for (int mf = 0; mf < 4; ++mf)
                #pragma unroll
                for (int nf = 0; nf < 4; ++nf)
                    acc2[mf][nf] = __builtin_amdgcn_mfma_f32_16x16x32_bf16(a2[mf], pb[cur][nf], acc2[mf][nf], 0, 0, 0);
            __builtin_amdgcn_s_setprio(0);
        }
    }

    // ---- BN2 + ReLU + partial dot with W3 (fp32), reduce 16 col-lanes ----
    float part[16];
    #pragma unroll
    for (int i = 0; i < 16; ++i) part[i] = 0.f;
    {
        float s2v[4], t2v[4], w3v[4];
        #pragma unroll
        for (int nf = 0; nf < 4; ++nf) {
            int col = n0 + nf * 16 + l15;
            s2v[nf] = s2[col]; t2v[nf] = t2[col]; w3v[nf] = W3[col];
        }
        #pragma unroll
        for (int mf = 0; mf < 4; ++mf)
            #pragma unroll
            for (int nf = 0; nf < 4; ++nf)
                #pragma unroll
                for (int i = 0; i < 4; ++i) {
                    float h = fmaxf(acc2[mf][nf][i] * s2v[nf] + t2v[nf], 0.0f);
                    part[mf * 4 + i] += h * w3v[nf];
                }
    }
    #pragma unroll
    for (int off = 1; off < 16; off <<= 1)
        #pragma unroll
        for (int i = 0; i < 16; ++i) part[i] += __shfl_xor(part[i], off, 64);

    if (l15 == 0) {
        #pragma unroll
        for (int mf = 0; mf < 4; ++mf)
            #pragma unroll
            for (int i = 0; i < 4; ++i)
                outb[w * 64 + mf * 16 + lq * 4 + i] = part[mf * 4 + i];
    }
    __syncthreads();
    if (tidx < 64) {
        float r = b3[0];
        #pragma unroll
        for (int ww = 0; ww < 8; ++ww) r += outb[ww * 64 + tidx];
        out[m0 + tidx] = r;
    }
#undef LOADB1
#undef LOADB2
#undef LDSA
#undef LOADA2
}

// ---------------- fallback scattered sampler (if ws too small for featT) ----------------
__global__ void sample_kernel(const float* __restrict__ feat,
                              const float* __restrict__ qp,
                              u16* __restrict__ fo)
{
    int tid = blockIdx.x * 256 + threadIdx.x;
    int p = tid >> 7;
    int c = tid & 127;
    int b = p >> 16;

    float qx = qp[p * 3 + 0], qy = qp[p * 3 + 1], qz = qp[p * 3 + 2];
    float x = fminf(fmaxf(qx * 63.0f, 0.0f), 63.0f);
    float y = fminf(fmaxf(qy * 63.0f, 0.0f), 63.0f);
    float z = fminf(fmaxf(qz * 63.0f, 0.0f), 63.0f);
    int x0 = (int)floorf(x), y0 = (int)floorf(y), z0 = (int)floorf(z);
    int x1 = min(x0 + 1, 63), y1 = min(y0 + 1, 63), z1 = min(z0 + 1, 63);
    float wx = x - (float)x0, wy = y - (float)y0, wz = z - (float)z0;

    const float* fb = feat + ((size_t)(b * NC + c) << 18);
    int zy00 = z0 * 4096 + y0 * 64, zy01 = z0 * 4096 + y1 * 64;
    int zy10 = z1 * 4096 + y0 * 64, zy11 = z1 * 4096 + y1 * 64;
    float f000 = fb[zy00 + x0], f001 = fb[zy00 + x1];
    float f010 = fb[zy01 + x0], f011 = fb[zy01 + x1];
    float f100 = fb[zy10 + x0], f101 = fb[zy10 + x1];
    float f110 = fb[zy11 + x0], f111 = fb[zy11 + x1];

    float omx = 1.0f - wx;
    float c00 = f000 * omx + f001 * wx;
    float c01 = f010 * omx + f011 * wx;
    float c10 = f100 * omx + f101 * wx;
    float c11 = f110 * omx + f111 * wx;
    float omy = 1.0f - wy;
    float c0 = c00 * omy + c01 * wy;
    float c1 = c10 * omy + c11 * wy;
    float v  = c0 * (1.0f - wz) + c1 * wz;
    fo[(size_t)p * 128 + c] = f2bf(v);
}

extern "C" void kernel_launch(void* const* d_in, const int* in_sizes, int n_in,
                              void* d_out, int out_size, void* d_ws, size_t ws_size,
                              hipStream_t stream)
{
    const float* feat = (const float*)d_in[0];
    const float* qp   = (const float*)d_in[1];
    const float* W1   = (const float*)d_in[2];
    const float* b1   = (const float*)d_in[3];
    const float* g1   = (const float*)d_in[4];
    const float* be1  = (const float*)d_in[5];
    const float* m1   = (const float*)d_in[6];
    const float* v1   = (const float*)d_in[7];
    const float* W2   = (const float*)d_in[8];
    const float* b2   = (const float*)d_in[9];
    const float* g2   = (const float*)d_in[10];
    const float* be2  = (const float*)d_in[11];
    const float* m2   = (const float*)d_in[12];
    const float* v2   = (const float*)d_in[13];
    const float* W3   = (const float*)d_in[14];
    const float* b3   = (const float*)d_in[15];

    char* ws = (char*)d_ws;
    u16*   W1p   = (u16*)(ws);                    // 131072 B
    u16*   W2p   = (u16*)(ws + 131072);           // 524288 B
    float* s1    = (float*)(ws + 655360);
    float* t1    = (float*)(ws + 657408);
    float* s2    = (float*)(ws + 659456);
    float* t2    = (float*)(ws + 661504);
    u16*   feats = (u16*)(ws + 663552);           // 33554432 B (fallback only)
    u16*   featT = (u16*)(ws + 663552 + 33554432);// 134217728 B
    const size_t needed = 663552 + 33554432 + 134217728;

    if (ws_size >= needed) {
        transpose_kernel<<<16384 + 128, 256, 0, stream>>>(
            feat, featT, W1, W2, b1, g1, be1, m1, v1, b2, g2, be2, m2, v2,
            W1p, W2p, s1, t1, s2, t2);
        fused_kernel<true><<<NTILE, 512, 0, stream>>>(featT, feats, qp, W1p, W2p,
                                                      s1, t1, s2, t2, W3, b3, (float*)d_out);
    } else {
        prep_kernel<<<128, 256, 0, stream>>>(W1, W2, b1, g1, be1, m1, v1,
                                             b2, g2, be2, m2, v2,
                                             W1p, W2p, s1, t1, s2, t2);
        sample_kernel<<<(MTOT * 128) / 256, 256, 0, stream>>>(feat, qp, feats);
        fused_kernel<false><<<NTILE, 512, 0, stream>>>(featT, feats, qp, W1p, W2p,
                                                       s1, t1, s2, t2, W3, b3, (float*)d_out);
    }
}